// Round 7
// baseline (1108.738 us; speedup 1.0000x reference)
//
#include <hip/hip_runtime.h>
#include <hip/hip_bf16.h>

// ---------------- problem constants ----------------
#define BB   2
#define TT   8
#define YY   128
#define XX   128
#define CINv 128
#define COUTv 64
#define YOv  255
#define XOv  255
#define NVOX 262144
#define NSITES (BB*TT*YY*XX)                 // 262,144 input sites
#define CAP  16
#define OUT_SITES (BB*TT*YOv*XOv)            // 1,040,400
#define OUT_ELEMS ((size_t)OUT_SITES*COUTv)  // 66,585,600

typedef float  f32x4  __attribute__((ext_vector_type(4)));
typedef __bf16 bf16x8 __attribute__((ext_vector_type(8)));
typedef unsigned int u32x4 __attribute__((ext_vector_type(4)));

union FragU { u32x4 u; bf16x8 b; };
union Pack8 { unsigned short s[8]; u32x4 u; };

// ---------------- workspace layout (bytes) ----------------
constexpr size_t OFF_STATS = 0;                          // gsum[64]@0, gsq[64]@256, ncnt@512
constexpr size_t OFF_CNT   = 1024;                       // 262144*4 = 1,048,576
constexpr size_t ZERO_BYTES= OFF_CNT + 1048576;          // 1,049,600
constexpr size_t OFF_DBF   = ZERO_BYTES;                 // 262144*128*2 = 67,108,864
constexpr size_t OFF_PB    = OFF_DBF + 67108864;         // 27*16*64*8*2 = 442,368
constexpr size_t OFF_MASK  = OFF_PB + 442368;            // 1,040,400 (pad 1 MiB)
constexpr size_t OFF_SS    = OFF_MASK + 1048576;         // (unused now)
// idx (used only by k_count/k_gather) aliases outb (used only by k_conv/k_norm)
constexpr size_t OFF_IDX   = OFF_SS + 1024;              // 262144*16*4 = 16,777,216
constexpr size_t OFF_OUTB  = OFF_IDX;                    // OUT_ELEMS*2 = 133,171,200
// total ~193.4 MiB

__device__ __forceinline__ unsigned short f2bf(float f) {
    unsigned u = __float_as_uint(f);
    u += 0x7fffu + ((u >> 16) & 1u);       // round-to-nearest-even
    return (unsigned short)(u >> 16);
}

__device__ __forceinline__ void gld16(const void* g, void* l) {
    __builtin_amdgcn_global_load_lds(
        (const __attribute__((address_space(1))) unsigned int*)g,
        (__attribute__((address_space(3))) unsigned int*)l, 16, 0, 0);
}

// ---------------- pass 1: per-site voxel lists ----------------
__global__ __launch_bounds__(256) void k_count(
    const int* __restrict__ cb, const int* __restrict__ ct,
    const int* __restrict__ cy, const int* __restrict__ cx,
    unsigned int* __restrict__ cnt, int* __restrict__ idx)
{
    int n = blockIdx.x * 256 + threadIdx.x;     // NVOX threads
    int site = ((cb[n] * TT + ct[n]) * YY + cy[n]) * XX + cx[n];
    unsigned slot = atomicAdd(cnt + site, 1u);
    if (slot < CAP) idx[site * CAP + slot] = n;  // P(overflow) ~ 4e-9 for Poisson(1)
}

// ---------------- pass 2: gather-sum feats -> bf16 dense grid ----------------
__global__ __launch_bounds__(256) void k_gather(
    const float* __restrict__ feats,
    const unsigned int* __restrict__ cnt, const int* __restrict__ idx,
    unsigned short* __restrict__ Dbf)
{
    int tid = blockIdx.x * 256 + threadIdx.x;   // NSITES*16 threads
    int site = tid >> 4;
    int c8 = (tid & 15) * 8;
    unsigned c = cnt[site]; if (c > CAP) c = CAP;
    float a[8] = {0.f,0.f,0.f,0.f,0.f,0.f,0.f,0.f};
    const int* ip = idx + (size_t)site * CAP;
    if (c) {
        const int4 i4 = *(const int4*)ip;        // first 4 slots, one load
        int nv[4] = { i4.x, i4.y, i4.z, i4.w };
        #pragma unroll
        for (int v = 0; v < 4; ++v) {
            if ((unsigned)v < c) {
                int n = nv[v];
                const float4 f0 = *(const float4*)(feats + (size_t)n * CINv + c8);
                const float4 f1 = *(const float4*)(feats + (size_t)n * CINv + c8 + 4);
                a[0] += f0.x; a[1] += f0.y; a[2] += f0.z; a[3] += f0.w;
                a[4] += f1.x; a[5] += f1.y; a[6] += f1.z; a[7] += f1.w;
            }
        }
        for (unsigned v = 4; v < c; ++v) {       // rare tail (P ~ 0.004)
            int n = ip[v];
            const float4 f0 = *(const float4*)(feats + (size_t)n * CINv + c8);
            const float4 f1 = *(const float4*)(feats + (size_t)n * CINv + c8 + 4);
            a[0] += f0.x; a[1] += f0.y; a[2] += f0.z; a[3] += f0.w;
            a[4] += f1.x; a[5] += f1.y; a[6] += f1.z; a[7] += f1.w;
        }
    }
    Pack8 p;
    #pragma unroll
    for (int j = 0; j < 8; ++j) p.s[j] = f2bf(a[j]);
    *(u32x4*)(Dbf + (size_t)site * CINv + c8) = p.u;
}

// ---------------- pass 3: pack weights into MFMA B-fragments ----------------
// PB layout: [w(27)][f(16)=kc*4+nt][lane(64)][8 bf16]  (16 KB per tap tile)
__global__ __launch_bounds__(64) void k_pack(
    const float* __restrict__ W, unsigned short* __restrict__ PB)
{
    int f = blockIdx.x;                 // 0..431 = w*16 + kc*4 + nt
    int w  = f >> 4;
    int kc = (f >> 2) & 3;
    int nt = f & 3;
    int lane = threadIdx.x;
    int q = lane >> 4, col = lane & 15;
    Pack8 p;
    #pragma unroll
    for (int j = 0; j < 8; ++j) {
        int k  = kc * 32 + q * 8 + j;
        int nn = nt * 16 + col;
        p.s[j] = f2bf(W[((size_t)w * CINv + k) * COUTv + nn]);
    }
    *(u32x4*)(PB + ((size_t)f * 64 + lane) * 8) = p.u;
}

// ---------------- pass 4: active-site mask + count ----------------
__global__ __launch_bounds__(256) void k_mask(
    const unsigned int* __restrict__ occ,
    unsigned char* __restrict__ mask, unsigned int* __restrict__ ncnt)
{
    int s = blockIdx.x * 256 + threadIdx.x;
    bool found = false;
    if (s < OUT_SITES) {
        int xo = s % XOv; int r = s / XOv;
        int yo = r % YOv; r /= YOv;
        int to = r & 7;   int b = r >> 3;
        int cts[3]; int ntc = 0;
        for (int kt = 0; kt < 3; ++kt) { int c = to + 1 - kt; if (c >= 0 && c < TT) cts[ntc++] = c; }
        int cys[2]; int nyc;
        if (yo & 1) { cys[0] = (yo + 1) >> 1; cys[1] = (yo - 1) >> 1; nyc = 2; }
        else        { cys[0] = yo >> 1; nyc = 1; }
        int cxs[2]; int nxc;
        if (xo & 1) { cxs[0] = (xo + 1) >> 1; cxs[1] = (xo - 1) >> 1; nxc = 2; }
        else        { cxs[0] = xo >> 1; nxc = 1; }
        for (int i = 0; i < ntc && !found; ++i)
            for (int j = 0; j < nyc && !found; ++j)
                for (int k = 0; k < nxc && !found; ++k)
                    if (occ[((b * TT + cts[i]) * YY + cys[j]) * XX + cxs[k]]) found = true;
        mask[s] = found ? 1 : 0;
    }
    unsigned long long bal = __ballot(found);
    if ((threadIdx.x & 63) == 0) {
        unsigned c = (unsigned)__popcll(bal);
        if (c) atomicAdd(ncnt, c);
    }
}

// ---------------- pass 5: MFMA transpose-conv, dual-row, LDS-staged B -------
// Structure identical to the proven dual-row kernel (round 2 / round 5).
// Block -> row map v6: BALANCED per-XCD + dense cy window.
//   xcd = bid&7; u = bid>>3 (per-XCD issue order).
//   (b,to) = u&15  -> every XCD runs ALL (b,to) combos => identical total
//   work per XCD (round-5's to-pinned map had 5-vs-6-stage imbalance ->
//   XCD idle tails, occupancy 14%).
//   v = xcd*16 + (u>>4): each XCD owns a contiguous band of 16 of the 128
//   parity-interleaved row-pair slots; yo0 = 4*(v>>1) + (v&1).
//   Concurrent window (~96 blocks/XCD at 3 blocks/CU) = ~6 cy values x 16
//   (b,ct) planes ~= 3-4 MB Dbf -> stays XCD-L2 resident (round 5 proved
//   the window model: FETCH 245 -> 89 MB).
// Occupancy: __launch_bounds__(256,3) -> 3 blocks/CU (VGPR 120 < 170 cap,
// LDS 3*48.5 KB = 146 KB < 160 KB) for latency hiding across block-stages.

#define MFMA_BF16(A, B, C) __builtin_amdgcn_mfma_f32_16x16x32_bf16((A), (B), (C), 0, 0, 0)

#define BPASS2(bt, SLOT) do {                                                            \
    _Pragma("unroll")                                                                    \
    for (int kc = 0; kc < 4; ++kc) {                                                     \
        FragU Bf[4];                                                                     \
        _Pragma("unroll")                                                                \
        for (int nt = 0; nt < 4; ++nt)                                                   \
            Bf[nt].u = *(const u32x4*)((bt) + (size_t)((kc * 4 + nt) * 64 + lane) * 8);  \
        _Pragma("unroll")                                                                \
        for (int nt = 0; nt < 4; ++nt) {                                                 \
            acc0[SLOT][nt]     = MFMA_BF16(Aa0[kc].b, Bf[nt].b, acc0[SLOT][nt]);         \
            acc0[SLOT + 2][nt] = MFMA_BF16(Ab0[kc].b, Bf[nt].b, acc0[SLOT + 2][nt]);     \
            acc1[SLOT][nt]     = MFMA_BF16(Aa1[kc].b, Bf[nt].b, acc1[SLOT][nt]);         \
            acc1[SLOT + 2][nt] = MFMA_BF16(Ab1[kc].b, Bf[nt].b, acc1[SLOT + 2][nt]);     \
        }                                                                                \
    } } while (0)

__global__ __launch_bounds__(256, 3) void k_conv(
    const unsigned short* __restrict__ Dbf,
    const unsigned short* __restrict__ PB,
    unsigned short* __restrict__ outb,
    float* __restrict__ gsum, float* __restrict__ gsq)
{
    const int lane = threadIdx.x & 63;
    const int wave = threadIdx.x >> 6;
    const int bid = blockIdx.x;

    // ---- balanced L2-local block->row map (bijective over 2048 blocks) ----
    const int xcd  = bid & 7;            // hw round-robin: bid%8 = XCD
    const int u    = bid >> 3;           // 0..255, execution-ordered per XCD
    const int bt   = u & 15;             // (b,to): all combos on every XCD
    const int b    = bt >> 3;
    const int to   = bt & 7;
    const int v    = xcd * 16 + (u >> 4);// 0..127: row-pair slot, banded per XCD
    const int yo0  = 4 * (v >> 1) + (v & 1);
    const bool has2 = (yo0 + 2 <= 254);  // false only for v=127 (yo0=253)

    const int m = lane & 15, q = lane >> 4;

    __shared__ __align__(16) unsigned short shB[3 * 16 * 64 * 8];   // 48 KB
    __shared__ float shsum[64], shsq[64];
    if (threadIdx.x < 64) { shsum[threadIdx.x] = 0.f; shsq[threadIdx.x] = 0.f; }

    int ycy[2], yky[2], ny;
    if ((yo0 & 1) == 0) { ny = 1; ycy[0] = yo0 >> 1; yky[0] = 1; }
    else { ny = 2; ycy[0] = (yo0 + 1) >> 1; yky[0] = 0; ycy[1] = (yo0 - 1) >> 1; yky[1] = 2; }

    f32x4 acc0[4][4], acc1[4][4];   // [slot: a-even, a-odd, b-even, b-odd][nt]
    #pragma unroll
    for (int ch = 0; ch < 4; ++ch)
        #pragma unroll
        for (int nt = 0; nt < 4; ++nt) {
            acc0[ch][nt] = (f32x4){0.f, 0.f, 0.f, 0.f};
            acc1[ch][nt] = (f32x4){0.f, 0.f, 0.f, 0.f};
        }

    for (int kt = 0; kt < 3; ++kt) {
        int ct = to + 1 - kt;
        if (ct < 0 || ct >= TT) continue;        // uniform over block
        for (int iy = 0; iy < ny; ++iy) {        // uniform over block
            __syncthreads();                      // protect LDS from prior readers
            {
                const char* gsrc = (const char*)PB + (size_t)((kt * 3 + yky[iy]) * 3) * 16384;
                char* ldst = (char*)shB;
                #pragma unroll
                for (int r = 0; r < 12; ++r)
                    gld16(gsrc + r * 4096 + threadIdx.x * 16,
                          ldst + r * 4096 + wave * 1024);
            }
            // A0 (cxoff=0) for BOTH rows, pre-barrier: drained with staging.
            int cy0 = ycy[iy];
            int cy1 = has2 ? cy0 + 1 : cy0;                    // clamp for singleton
            size_t plane0 = ((size_t)((b * TT + ct) * YY + cy0)) * XX;
            size_t plane1 = ((size_t)((b * TT + ct) * YY + cy1)) * XX;
            FragU Aa0[4], Ab0[4], Aa1[4], Ab1[4];
            {
                const unsigned short* pa0 = Dbf + (plane0 + (size_t)(2 * wave * 16 + m)) * CINv;
                const unsigned short* pb0 = Dbf + (plane0 + (size_t)((2 * wave + 1) * 16 + m)) * CINv;
                const unsigned short* pa1 = Dbf + (plane1 + (size_t)(2 * wave * 16 + m)) * CINv;
                const unsigned short* pb1 = Dbf + (plane1 + (size_t)((2 * wave + 1) * 16 + m)) * CINv;
                #pragma unroll
                for (int kc = 0; kc < 4; ++kc) {
                    Aa0[kc].u = *(const u32x4*)(pa0 + kc * 32 + q * 8);
                    Ab0[kc].u = *(const u32x4*)(pb0 + kc * 32 + q * 8);
                    Aa1[kc].u = *(const u32x4*)(pa1 + kc * 32 + q * 8);
                    Ab1[kc].u = *(const u32x4*)(pb1 + kc * 32 + q * 8);
                }
            }
            __syncthreads();

            BPASS2(shB + 8192,  0);   // kx=1 -> even-parity outputs (A0)
            BPASS2(shB + 16384, 1);   // kx=2 -> odd-parity outputs  (A0)

            // A1 (cxoff=1) into the same registers (only the b-chunk can hit 128);
            // lines just touched by A0 -> L1/L2 hits.
            {
                int cxb1 = (2 * wave + 1) * 16 + m + 1; if (cxb1 > 127) cxb1 = 127;
                const unsigned short* pa0 = Dbf + (plane0 + (size_t)(2 * wave * 16 + m + 1)) * CINv;
                const unsigned short* pb0 = Dbf + (plane0 + (size_t)cxb1) * CINv;
                const unsigned short* pa1 = Dbf + (plane1 + (size_t)(2 * wave * 16 + m + 1)) * CINv;
                const unsigned short* pb1 = Dbf + (plane1 + (size_t)cxb1) * CINv;
                #pragma unroll
                for (int kc = 0; kc < 4; ++kc) {
                    Aa0[kc].u = *(const u32x4*)(pa0 + kc * 32 + q * 8);
                    Ab0[kc].u = *(const u32x4*)(pb0 + kc * 32 + q * 8);
                    Aa1[kc].u = *(const u32x4*)(pa1 + kc * 32 + q * 8);
                    Ab1[kc].u = *(const u32x4*)(pb1 + kc * 32 + q * 8);
                }
            }
            BPASS2(shB + 0, 1);       // kx=0 -> odd-parity outputs (A1)
        }
    }

    // epilogue: bf16 store + per-channel partial stats (both rows)
    float sl[4] = {0.f,0.f,0.f,0.f}, sq[4] = {0.f,0.f,0.f,0.f};
    {
        size_t rowbase = ((size_t)((b * TT + to) * YOv + yo0)) * XOv;
        #pragma unroll
        for (int ch = 0; ch < 4; ++ch) {
            int cb8 = 2 * wave + (ch >> 1);
            int px = ch & 1;
            #pragma unroll
            for (int nt = 0; nt < 4; ++nt) {
                int c = nt * 16 + m;
                #pragma unroll
                for (int i = 0; i < 4; ++i) {
                    int r = q * 4 + i;
                    int xo = 2 * (cb8 * 16 + r) + px;
                    if (xo < XOv) {
                        float v2 = acc0[ch][nt][i];
                        outb[(rowbase + xo) * COUTv + c] = f2bf(v2);
                        sl[nt] += v2; sq[nt] += v2 * v2;
                    }
                }
            }
        }
    }
    if (has2) {
        size_t rowbase = ((size_t)((b * TT + to) * YOv + (yo0 + 2))) * XOv;
        #pragma unroll
        for (int ch = 0; ch < 4; ++ch) {
            int cb8 = 2 * wave + (ch >> 1);
            int px = ch & 1;
            #pragma unroll
            for (int nt = 0; nt < 4; ++nt) {
                int c = nt * 16 + m;
                #pragma unroll
                for (int i = 0; i < 4; ++i) {
                    int r = q * 4 + i;
                    int xo = 2 * (cb8 * 16 + r) + px;
                    if (xo < XOv) {
                        float v2 = acc1[ch][nt][i];
                        outb[(rowbase + xo) * COUTv + c] = f2bf(v2);
                        sl[nt] += v2; sq[nt] += v2 * v2;
                    }
                }
            }
        }
    }
    #pragma unroll
    for (int nt = 0; nt < 4; ++nt) {
        sl[nt] += __shfl_xor(sl[nt], 16); sl[nt] += __shfl_xor(sl[nt], 32);
        sq[nt] += __shfl_xor(sq[nt], 16); sq[nt] += __shfl_xor(sq[nt], 32);
    }
    if (lane < 16) {
        #pragma unroll
        for (int nt = 0; nt < 4; ++nt) {
            atomicAdd(&shsum[nt * 16 + lane], sl[nt]);
            atomicAdd(&shsq [nt * 16 + lane], sq[nt]);
        }
    }
    __syncthreads();
    if (threadIdx.x < 64) {
        unsafeAtomicAdd(&gsum[threadIdx.x], shsum[threadIdx.x]);
        unsafeAtomicAdd(&gsq [threadIdx.x], shsq [threadIdx.x]);
    }
}

// ---------------- pass 6: normalize + mask + relu (bf16 -> fp32) -------------
// k_final fused in: each block derives scale/shift from gsum/gsq/ncnt (L2-hot
// 768 B) in its first 64 lanes — one fewer kernel launch + stream bubble.
__global__ __launch_bounds__(256) void k_norm(
    const unsigned short* __restrict__ outb, float* __restrict__ out,
    const unsigned char* __restrict__ mask,
    const float* __restrict__ gsum, const float* __restrict__ gsq,
    const unsigned int* __restrict__ ncnt,
    const float* __restrict__ gamma, const float* __restrict__ beta)
{
    __shared__ float ssc[64], ssh[64];
    if (threadIdx.x < 64) {
        int c = threadIdx.x;
        float nf = (float)max(*ncnt, 1u);
        float mean = gsum[c] / nf;
        float var  = gsq[c] / nf - mean * mean;
        float rstd = rsqrtf(var + 1e-5f);
        float sc = rstd * gamma[c];
        ssc[c] = sc;
        ssh[c] = beta[c] - mean * sc;
    }
    __syncthreads();
    size_t t = (size_t)blockIdx.x * 256 + threadIdx.x;
    size_t e = t * 8;
    if (e >= OUT_ELEMS) return;
    Pack8 p; p.u = *(const u32x4*)(outb + e);
    int c = (int)(e & 63);
    size_t site = e >> 6;
    float4 v0, v1;
    if (mask[site]) {
        float w[8];
        #pragma unroll
        for (int j = 0; j < 8; ++j) {
            float f = __uint_as_float((unsigned)p.s[j] << 16);
            w[j] = fmaxf(fmaf(f, ssc[c + j], ssh[c + j]), 0.f);
        }
        v0 = make_float4(w[0], w[1], w[2], w[3]);
        v1 = make_float4(w[4], w[5], w[6], w[7]);
    } else {
        v0 = make_float4(0.f, 0.f, 0.f, 0.f);
        v1 = v0;
    }
    *(float4*)(out + e) = v0;
    *(float4*)(out + e + 4) = v1;
}

// ---------------- launch ----------------
extern "C" void kernel_launch(void* const* d_in, const int* in_sizes, int n_in,
                              void* d_out, int out_size, void* d_ws, size_t ws_size,
                              hipStream_t stream)
{
    const float* feats = (const float*)d_in[0];
    const float* W     = (const float*)d_in[1];
    const float* gamma = (const float*)d_in[2];
    const float* beta  = (const float*)d_in[3];
    const int* cb = (const int*)d_in[4];
    const int* ct = (const int*)d_in[5];
    const int* cy = (const int*)d_in[6];
    const int* cx = (const int*)d_in[7];
    float* out = (float*)d_out;

    char* ws = (char*)d_ws;
    float*          gsum = (float*)(ws + OFF_STATS);
    float*          gsq  = gsum + 64;
    unsigned int*   ncnt = (unsigned int*)(ws + OFF_STATS + 512);
    unsigned int*   cnt  = (unsigned int*)(ws + OFF_CNT);
    unsigned short* Dbf  = (unsigned short*)(ws + OFF_DBF);
    unsigned short* PB   = (unsigned short*)(ws + OFF_PB);
    unsigned char*  mask = (unsigned char*)(ws + OFF_MASK);
    int*            idx  = (int*)(ws + OFF_IDX);
    unsigned short* outb = (unsigned short*)(ws + OFF_OUTB);   // aliases idx (ordered)

    hipMemsetAsync(d_ws, 0, ZERO_BYTES, stream);

    k_count<<<NVOX / 256, 256, 0, stream>>>(cb, ct, cy, cx, cnt, idx);
    k_gather<<<NSITES * 16 / 256, 256, 0, stream>>>(feats, cnt, idx, Dbf);
    k_pack<<<27 * 16, 64, 0, stream>>>(W, PB);
    k_mask<<<(OUT_SITES + 255) / 256, 256, 0, stream>>>(cnt, mask, ncnt);
    k_conv<<<2048, 256, 0, stream>>>(Dbf, PB, outb, gsum, gsq);
    k_norm<<<(int)((OUT_ELEMS / 8 + 255) / 256), 256, 0, stream>>>(
        outb, out, mask, gsum, gsq, ncnt, gamma, beta);
}

// Round 8
// 830.318 us; speedup vs baseline: 1.3353x; 1.3353x over previous
//
#include <hip/hip_runtime.h>
#include <hip/hip_bf16.h>

// ---------------- problem constants ----------------
#define BB   2
#define TT   8
#define YY   128
#define XX   128
#define CINv 128
#define COUTv 64
#define YOv  255
#define XOv  255
#define NVOX 262144
#define NSITES (BB*TT*YY*XX)                 // 262,144 input sites
#define CAP  16
#define OUT_SITES (BB*TT*YOv*XOv)            // 1,040,400
#define OUT_ELEMS ((size_t)OUT_SITES*COUTv)  // 66,585,600

typedef float  f32x4  __attribute__((ext_vector_type(4)));
typedef __bf16 bf16x8 __attribute__((ext_vector_type(8)));
typedef unsigned int u32x4 __attribute__((ext_vector_type(4)));

union FragU { u32x4 u; bf16x8 b; };
union Pack8 { unsigned short s[8]; u32x4 u; };

// ---------------- workspace layout (bytes) ----------------
constexpr size_t OFF_STATS = 0;                          // gsum[64]@0, gsq[64]@256, ncnt@512
constexpr size_t OFF_CNT   = 1024;                       // 262144*4 = 1,048,576
constexpr size_t ZERO_BYTES= OFF_CNT + 1048576;          // 1,049,600
constexpr size_t OFF_DBF   = ZERO_BYTES;                 // 262144*128*2 = 67,108,864
constexpr size_t OFF_PB    = OFF_DBF + 67108864;         // 27*16*64*8*2 = 442,368
constexpr size_t OFF_MASK  = OFF_PB + 442368;            // 1,040,400 (pad 1 MiB)
constexpr size_t OFF_SS    = OFF_MASK + 1048576;         // (unused now)
// idx (used only by k_count/k_gather) aliases outb (used only by k_conv/k_norm)
constexpr size_t OFF_IDX   = OFF_SS + 1024;              // 262144*16*4 = 16,777,216
constexpr size_t OFF_OUTB  = OFF_IDX;                    // OUT_ELEMS*2 = 133,171,200
// total ~193.4 MiB

__device__ __forceinline__ unsigned short f2bf(float f) {
    unsigned u = __float_as_uint(f);
    u += 0x7fffu + ((u >> 16) & 1u);       // round-to-nearest-even
    return (unsigned short)(u >> 16);
}

__device__ __forceinline__ void gld16(const void* g, void* l) {
    __builtin_amdgcn_global_load_lds(
        (const __attribute__((address_space(1))) unsigned int*)g,
        (__attribute__((address_space(3))) unsigned int*)l, 16, 0, 0);
}

// ---------------- pass 1: per-site voxel lists ----------------
__global__ __launch_bounds__(256) void k_count(
    const int* __restrict__ cb, const int* __restrict__ ct,
    const int* __restrict__ cy, const int* __restrict__ cx,
    unsigned int* __restrict__ cnt, int* __restrict__ idx)
{
    int n = blockIdx.x * 256 + threadIdx.x;     // NVOX threads
    int site = ((cb[n] * TT + ct[n]) * YY + cy[n]) * XX + cx[n];
    unsigned slot = atomicAdd(cnt + site, 1u);
    if (slot < CAP) idx[site * CAP + slot] = n;  // P(overflow) ~ 4e-9 for Poisson(1)
}

// ---------------- pass 2: gather-sum feats -> bf16 dense grid ----------------
__global__ __launch_bounds__(256) void k_gather(
    const float* __restrict__ feats,
    const unsigned int* __restrict__ cnt, const int* __restrict__ idx,
    unsigned short* __restrict__ Dbf)
{
    int tid = blockIdx.x * 256 + threadIdx.x;   // NSITES*16 threads
    int site = tid >> 4;
    int c8 = (tid & 15) * 8;
    unsigned c = cnt[site]; if (c > CAP) c = CAP;
    float a[8] = {0.f,0.f,0.f,0.f,0.f,0.f,0.f,0.f};
    const int* ip = idx + (size_t)site * CAP;
    if (c) {
        const int4 i4 = *(const int4*)ip;        // first 4 slots, one load
        int nv[4] = { i4.x, i4.y, i4.z, i4.w };
        #pragma unroll
        for (int v = 0; v < 4; ++v) {
            if ((unsigned)v < c) {
                int n = nv[v];
                const float4 f0 = *(const float4*)(feats + (size_t)n * CINv + c8);
                const float4 f1 = *(const float4*)(feats + (size_t)n * CINv + c8 + 4);
                a[0] += f0.x; a[1] += f0.y; a[2] += f0.z; a[3] += f0.w;
                a[4] += f1.x; a[5] += f1.y; a[6] += f1.z; a[7] += f1.w;
            }
        }
        for (unsigned v = 4; v < c; ++v) {       // rare tail (P ~ 0.004)
            int n = ip[v];
            const float4 f0 = *(const float4*)(feats + (size_t)n * CINv + c8);
            const float4 f1 = *(const float4*)(feats + (size_t)n * CINv + c8 + 4);
            a[0] += f0.x; a[1] += f0.y; a[2] += f0.z; a[3] += f0.w;
            a[4] += f1.x; a[5] += f1.y; a[6] += f1.z; a[7] += f1.w;
        }
    }
    Pack8 p;
    #pragma unroll
    for (int j = 0; j < 8; ++j) p.s[j] = f2bf(a[j]);
    *(u32x4*)(Dbf + (size_t)site * CINv + c8) = p.u;
}

// ---------------- pass 3: pack weights into MFMA B-fragments ----------------
// PB layout: [w(27)][f(16)=kc*4+nt][lane(64)][8 bf16]  (16 KB per tap tile)
__global__ __launch_bounds__(64) void k_pack(
    const float* __restrict__ W, unsigned short* __restrict__ PB)
{
    int f = blockIdx.x;                 // 0..431 = w*16 + kc*4 + nt
    int w  = f >> 4;
    int kc = (f >> 2) & 3;
    int nt = f & 3;
    int lane = threadIdx.x;
    int q = lane >> 4, col = lane & 15;
    Pack8 p;
    #pragma unroll
    for (int j = 0; j < 8; ++j) {
        int k  = kc * 32 + q * 8 + j;
        int nn = nt * 16 + col;
        p.s[j] = f2bf(W[((size_t)w * CINv + k) * COUTv + nn]);
    }
    *(u32x4*)(PB + ((size_t)f * 64 + lane) * 8) = p.u;
}

// ---------------- pass 4: active-site mask + count ----------------
__global__ __launch_bounds__(256) void k_mask(
    const unsigned int* __restrict__ occ,
    unsigned char* __restrict__ mask, unsigned int* __restrict__ ncnt)
{
    int s = blockIdx.x * 256 + threadIdx.x;
    bool found = false;
    if (s < OUT_SITES) {
        int xo = s % XOv; int r = s / XOv;
        int yo = r % YOv; r /= YOv;
        int to = r & 7;   int b = r >> 3;
        int cts[3]; int ntc = 0;
        for (int kt = 0; kt < 3; ++kt) { int c = to + 1 - kt; if (c >= 0 && c < TT) cts[ntc++] = c; }
        int cys[2]; int nyc;
        if (yo & 1) { cys[0] = (yo + 1) >> 1; cys[1] = (yo - 1) >> 1; nyc = 2; }
        else        { cys[0] = yo >> 1; nyc = 1; }
        int cxs[2]; int nxc;
        if (xo & 1) { cxs[0] = (xo + 1) >> 1; cxs[1] = (xo - 1) >> 1; nxc = 2; }
        else        { cxs[0] = xo >> 1; nxc = 1; }
        for (int i = 0; i < ntc && !found; ++i)
            for (int j = 0; j < nyc && !found; ++j)
                for (int k = 0; k < nxc && !found; ++k)
                    if (occ[((b * TT + cts[i]) * YY + cys[j]) * XX + cxs[k]]) found = true;
        mask[s] = found ? 1 : 0;
    }
    unsigned long long bal = __ballot(found);
    if ((threadIdx.x & 63) == 0) {
        unsigned c = (unsigned)__popcll(bal);
        if (c) atomicAdd(ncnt, c);
    }
}

// ---------------- pass 5: MFMA transpose-conv, dual-row, LDS-staged B -------
// Structure identical to the proven dual-row kernel (round 2).
// Block -> row map: BALANCED per-XCD + dense cy window (round-6 design).
//   xcd = bid&7; u = bid>>3 (per-XCD issue order).
//   (b,to) = u&15  -> every XCD runs ALL (b,to) combos => identical work/XCD.
//   v = xcd*16 + (u>>4): contiguous band of 16 row-pair slots per XCD; the
//   ~96 concurrently-resident blocks/XCD touch a dense ~4 MB Dbf window ->
//   XCD-L2 resident (round 5 proved the window model: FETCH 245 -> 89 MB).
// __launch_bounds__(256, 2): EMPIRICAL. (256,3) made hipcc cap VGPR at 84 ->
// acc spill -> 950 MB scratch writes, conv 508 us (round 7). (256,2) gives
// VGPR=120, no spill; LDS (48.5 KB) already caps residency at 3 blocks/CU,
// and the bound is only a minimum, so nothing is lost.

#define MFMA_BF16(A, B, C) __builtin_amdgcn_mfma_f32_16x16x32_bf16((A), (B), (C), 0, 0, 0)

#define BPASS2(bt, SLOT) do {                                                            \
    _Pragma("unroll")                                                                    \
    for (int kc = 0; kc < 4; ++kc) {                                                     \
        FragU Bf[4];                                                                     \
        _Pragma("unroll")                                                                \
        for (int nt = 0; nt < 4; ++nt)                                                   \
            Bf[nt].u = *(const u32x4*)((bt) + (size_t)((kc * 4 + nt) * 64 + lane) * 8);  \
        _Pragma("unroll")                                                                \
        for (int nt = 0; nt < 4; ++nt) {                                                 \
            acc0[SLOT][nt]     = MFMA_BF16(Aa0[kc].b, Bf[nt].b, acc0[SLOT][nt]);         \
            acc0[SLOT + 2][nt] = MFMA_BF16(Ab0[kc].b, Bf[nt].b, acc0[SLOT + 2][nt]);     \
            acc1[SLOT][nt]     = MFMA_BF16(Aa1[kc].b, Bf[nt].b, acc1[SLOT][nt]);         \
            acc1[SLOT + 2][nt] = MFMA_BF16(Ab1[kc].b, Bf[nt].b, acc1[SLOT + 2][nt]);     \
        }                                                                                \
    } } while (0)

__global__ __launch_bounds__(256, 2) void k_conv(
    const unsigned short* __restrict__ Dbf,
    const unsigned short* __restrict__ PB,
    unsigned short* __restrict__ outb,
    float* __restrict__ gsum, float* __restrict__ gsq)
{
    const int lane = threadIdx.x & 63;
    const int wave = threadIdx.x >> 6;
    const int bid = blockIdx.x;

    // ---- balanced L2-local block->row map (bijective over 2048 blocks) ----
    const int xcd  = bid & 7;            // hw round-robin: bid%8 = XCD
    const int u    = bid >> 3;           // 0..255, execution-ordered per XCD
    const int bt   = u & 15;             // (b,to): all combos on every XCD
    const int b    = bt >> 3;
    const int to   = bt & 7;
    const int v    = xcd * 16 + (u >> 4);// 0..127: row-pair slot, banded per XCD
    const int yo0  = 4 * (v >> 1) + (v & 1);
    const bool has2 = (yo0 + 2 <= 254);  // false only for v=127 (yo0=253)

    const int m = lane & 15, q = lane >> 4;

    __shared__ __align__(16) unsigned short shB[3 * 16 * 64 * 8];   // 48 KB
    __shared__ float shsum[64], shsq[64];
    if (threadIdx.x < 64) { shsum[threadIdx.x] = 0.f; shsq[threadIdx.x] = 0.f; }

    int ycy[2], yky[2], ny;
    if ((yo0 & 1) == 0) { ny = 1; ycy[0] = yo0 >> 1; yky[0] = 1; }
    else { ny = 2; ycy[0] = (yo0 + 1) >> 1; yky[0] = 0; ycy[1] = (yo0 - 1) >> 1; yky[1] = 2; }

    f32x4 acc0[4][4], acc1[4][4];   // [slot: a-even, a-odd, b-even, b-odd][nt]
    #pragma unroll
    for (int ch = 0; ch < 4; ++ch)
        #pragma unroll
        for (int nt = 0; nt < 4; ++nt) {
            acc0[ch][nt] = (f32x4){0.f, 0.f, 0.f, 0.f};
            acc1[ch][nt] = (f32x4){0.f, 0.f, 0.f, 0.f};
        }

    for (int kt = 0; kt < 3; ++kt) {
        int ct = to + 1 - kt;
        if (ct < 0 || ct >= TT) continue;        // uniform over block
        for (int iy = 0; iy < ny; ++iy) {        // uniform over block
            __syncthreads();                      // protect LDS from prior readers
            {
                const char* gsrc = (const char*)PB + (size_t)((kt * 3 + yky[iy]) * 3) * 16384;
                char* ldst = (char*)shB;
                #pragma unroll
                for (int r = 0; r < 12; ++r)
                    gld16(gsrc + r * 4096 + threadIdx.x * 16,
                          ldst + r * 4096 + wave * 1024);
            }
            // A0 (cxoff=0) for BOTH rows, pre-barrier: drained with staging.
            int cy0 = ycy[iy];
            int cy1 = has2 ? cy0 + 1 : cy0;                    // clamp for singleton
            size_t plane0 = ((size_t)((b * TT + ct) * YY + cy0)) * XX;
            size_t plane1 = ((size_t)((b * TT + ct) * YY + cy1)) * XX;
            FragU Aa0[4], Ab0[4], Aa1[4], Ab1[4];
            {
                const unsigned short* pa0 = Dbf + (plane0 + (size_t)(2 * wave * 16 + m)) * CINv;
                const unsigned short* pb0 = Dbf + (plane0 + (size_t)((2 * wave + 1) * 16 + m)) * CINv;
                const unsigned short* pa1 = Dbf + (plane1 + (size_t)(2 * wave * 16 + m)) * CINv;
                const unsigned short* pb1 = Dbf + (plane1 + (size_t)((2 * wave + 1) * 16 + m)) * CINv;
                #pragma unroll
                for (int kc = 0; kc < 4; ++kc) {
                    Aa0[kc].u = *(const u32x4*)(pa0 + kc * 32 + q * 8);
                    Ab0[kc].u = *(const u32x4*)(pb0 + kc * 32 + q * 8);
                    Aa1[kc].u = *(const u32x4*)(pa1 + kc * 32 + q * 8);
                    Ab1[kc].u = *(const u32x4*)(pb1 + kc * 32 + q * 8);
                }
            }
            __syncthreads();

            BPASS2(shB + 8192,  0);   // kx=1 -> even-parity outputs (A0)
            BPASS2(shB + 16384, 1);   // kx=2 -> odd-parity outputs  (A0)

            // A1 (cxoff=1) into the same registers (only the b-chunk can hit 128);
            // lines just touched by A0 -> L1/L2 hits.
            {
                int cxb1 = (2 * wave + 1) * 16 + m + 1; if (cxb1 > 127) cxb1 = 127;
                const unsigned short* pa0 = Dbf + (plane0 + (size_t)(2 * wave * 16 + m + 1)) * CINv;
                const unsigned short* pb0 = Dbf + (plane0 + (size_t)cxb1) * CINv;
                const unsigned short* pa1 = Dbf + (plane1 + (size_t)(2 * wave * 16 + m + 1)) * CINv;
                const unsigned short* pb1 = Dbf + (plane1 + (size_t)cxb1) * CINv;
                #pragma unroll
                for (int kc = 0; kc < 4; ++kc) {
                    Aa0[kc].u = *(const u32x4*)(pa0 + kc * 32 + q * 8);
                    Ab0[kc].u = *(const u32x4*)(pb0 + kc * 32 + q * 8);
                    Aa1[kc].u = *(const u32x4*)(pa1 + kc * 32 + q * 8);
                    Ab1[kc].u = *(const u32x4*)(pb1 + kc * 32 + q * 8);
                }
            }
            BPASS2(shB + 0, 1);       // kx=0 -> odd-parity outputs (A1)
        }
    }

    // epilogue: bf16 store + per-channel partial stats (both rows)
    float sl[4] = {0.f,0.f,0.f,0.f}, sq[4] = {0.f,0.f,0.f,0.f};
    {
        size_t rowbase = ((size_t)((b * TT + to) * YOv + yo0)) * XOv;
        #pragma unroll
        for (int ch = 0; ch < 4; ++ch) {
            int cb8 = 2 * wave + (ch >> 1);
            int px = ch & 1;
            #pragma unroll
            for (int nt = 0; nt < 4; ++nt) {
                int c = nt * 16 + m;
                #pragma unroll
                for (int i = 0; i < 4; ++i) {
                    int r = q * 4 + i;
                    int xo = 2 * (cb8 * 16 + r) + px;
                    if (xo < XOv) {
                        float v2 = acc0[ch][nt][i];
                        outb[(rowbase + xo) * COUTv + c] = f2bf(v2);
                        sl[nt] += v2; sq[nt] += v2 * v2;
                    }
                }
            }
        }
    }
    if (has2) {
        size_t rowbase = ((size_t)((b * TT + to) * YOv + (yo0 + 2))) * XOv;
        #pragma unroll
        for (int ch = 0; ch < 4; ++ch) {
            int cb8 = 2 * wave + (ch >> 1);
            int px = ch & 1;
            #pragma unroll
            for (int nt = 0; nt < 4; ++nt) {
                int c = nt * 16 + m;
                #pragma unroll
                for (int i = 0; i < 4; ++i) {
                    int r = q * 4 + i;
                    int xo = 2 * (cb8 * 16 + r) + px;
                    if (xo < XOv) {
                        float v2 = acc1[ch][nt][i];
                        outb[(rowbase + xo) * COUTv + c] = f2bf(v2);
                        sl[nt] += v2; sq[nt] += v2 * v2;
                    }
                }
            }
        }
    }
    #pragma unroll
    for (int nt = 0; nt < 4; ++nt) {
        sl[nt] += __shfl_xor(sl[nt], 16); sl[nt] += __shfl_xor(sl[nt], 32);
        sq[nt] += __shfl_xor(sq[nt], 16); sq[nt] += __shfl_xor(sq[nt], 32);
    }
    if (lane < 16) {
        #pragma unroll
        for (int nt = 0; nt < 4; ++nt) {
            atomicAdd(&shsum[nt * 16 + lane], sl[nt]);
            atomicAdd(&shsq [nt * 16 + lane], sq[nt]);
        }
    }
    __syncthreads();
    if (threadIdx.x < 64) {
        unsafeAtomicAdd(&gsum[threadIdx.x], shsum[threadIdx.x]);
        unsafeAtomicAdd(&gsq [threadIdx.x], shsq [threadIdx.x]);
    }
}

// ---------------- pass 6: normalize + mask + relu (bf16 -> fp32) -------------
// k_final fused in: each block derives scale/shift from gsum/gsq/ncnt (L2-hot
// 768 B) in its first 64 lanes — one fewer kernel launch + stream bubble.
__global__ __launch_bounds__(256) void k_norm(
    const unsigned short* __restrict__ outb, float* __restrict__ out,
    const unsigned char* __restrict__ mask,
    const float* __restrict__ gsum, const float* __restrict__ gsq,
    const unsigned int* __restrict__ ncnt,
    const float* __restrict__ gamma, const float* __restrict__ beta)
{
    __shared__ float ssc[64], ssh[64];
    if (threadIdx.x < 64) {
        int c = threadIdx.x;
        float nf = (float)max(*ncnt, 1u);
        float mean = gsum[c] / nf;
        float var  = gsq[c] / nf - mean * mean;
        float rstd = rsqrtf(var + 1e-5f);
        float sc = rstd * gamma[c];
        ssc[c] = sc;
        ssh[c] = beta[c] - mean * sc;
    }
    __syncthreads();
    size_t t = (size_t)blockIdx.x * 256 + threadIdx.x;
    size_t e = t * 8;
    if (e >= OUT_ELEMS) return;
    Pack8 p; p.u = *(const u32x4*)(outb + e);
    int c = (int)(e & 63);
    size_t site = e >> 6;
    float4 v0, v1;
    if (mask[site]) {
        float w[8];
        #pragma unroll
        for (int j = 0; j < 8; ++j) {
            float f = __uint_as_float((unsigned)p.s[j] << 16);
            w[j] = fmaxf(fmaf(f, ssc[c + j], ssh[c + j]), 0.f);
        }
        v0 = make_float4(w[0], w[1], w[2], w[3]);
        v1 = make_float4(w[4], w[5], w[6], w[7]);
    } else {
        v0 = make_float4(0.f, 0.f, 0.f, 0.f);
        v1 = v0;
    }
    *(float4*)(out + e) = v0;
    *(float4*)(out + e + 4) = v1;
}

// ---------------- launch ----------------
extern "C" void kernel_launch(void* const* d_in, const int* in_sizes, int n_in,
                              void* d_out, int out_size, void* d_ws, size_t ws_size,
                              hipStream_t stream)
{
    const float* feats = (const float*)d_in[0];
    const float* W     = (const float*)d_in[1];
    const float* gamma = (const float*)d_in[2];
    const float* beta  = (const float*)d_in[3];
    const int* cb = (const int*)d_in[4];
    const int* ct = (const int*)d_in[5];
    const int* cy = (const int*)d_in[6];
    const int* cx = (const int*)d_in[7];
    float* out = (float*)d_out;

    char* ws = (char*)d_ws;
    float*          gsum = (float*)(ws + OFF_STATS);
    float*          gsq  = gsum + 64;
    unsigned int*   ncnt = (unsigned int*)(ws + OFF_STATS + 512);
    unsigned int*   cnt  = (unsigned int*)(ws + OFF_CNT);
    unsigned short* Dbf  = (unsigned short*)(ws + OFF_DBF);
    unsigned short* PB   = (unsigned short*)(ws + OFF_PB);
    unsigned char*  mask = (unsigned char*)(ws + OFF_MASK);
    int*            idx  = (int*)(ws + OFF_IDX);
    unsigned short* outb = (unsigned short*)(ws + OFF_OUTB);   // aliases idx (ordered)

    hipMemsetAsync(d_ws, 0, ZERO_BYTES, stream);

    k_count<<<NVOX / 256, 256, 0, stream>>>(cb, ct, cy, cx, cnt, idx);
    k_gather<<<NSITES * 16 / 256, 256, 0, stream>>>(feats, cnt, idx, Dbf);
    k_pack<<<27 * 16, 64, 0, stream>>>(W, PB);
    k_mask<<<(OUT_SITES + 255) / 256, 256, 0, stream>>>(cnt, mask, ncnt);
    k_conv<<<2048, 256, 0, stream>>>(Dbf, PB, outb, gsum, gsq);
    k_norm<<<(int)((OUT_ELEMS / 8 + 255) / 256), 256, 0, stream>>>(
        outb, out, mask, gsum, gsq, ncnt, gamma, beta);
}